// Round 5
// baseline (1322.320 us; speedup 1.0000x reference)
//
#include <hip/hip_runtime.h>
#include <stdint.h>

// ---------------------------------------------------------------------------
// Decoder: GRU(seq) + attention + dense + vocab projection
// H=512, V=32000, B=16, Td=Te=64
// Round 5:
//  - GRU: NO grid barrier. h state exchanged as (fp32,value / u32,tag) 8-byte
//    pairs via relaxed agent-scope (sc1) atomics; consumers poll tags
//    directly. Self-timed wave-level dataflow (WAR-safe: wave w advances past
//    step s only after wave w of every block wrote step-s outputs, which is
//    after their step s-1 reads; batch->wave mapping identical everywhere).
//  - All prep (zero + 5 hi/lo splits + W_out convert) fused into one kernel.
//  - GEMMs: split-bf16 MFMA (AhBh+AhBl+AlBh), logits plain bf16 MFMA.
// ---------------------------------------------------------------------------

#define Hdim 512
#define Vdim 32000
#define Bdim 16
#define Tdim 64
#define BT   1024   // B*Td rows
#define GRU_BLOCKS 128

typedef __attribute__((ext_vector_type(8))) short bf16x8;
typedef __attribute__((ext_vector_type(4))) float f32x4;

static __device__ __forceinline__ unsigned short f2bf(float f) {
    unsigned u = __float_as_uint(f);
    u = u + 0x7FFFu + ((u >> 16) & 1u);   // RNE
    return (unsigned short)(u >> 16);
}
static __device__ __forceinline__ float bf2f(unsigned short h) {
    return __uint_as_float((unsigned)h << 16);
}

// --------------------------- fused prep kernel -----------------------------
// zero hpair+zbias, convert W_out->bf16, split 5 fp32 arrays into hi/lo bf16.

static __device__ __forceinline__ void split4(const float* __restrict__ in,
                                              unsigned short* __restrict__ hi,
                                              unsigned short* __restrict__ lo,
                                              int i) {
    float4 v = *(const float4*)(in + i);
    float f[4] = {v.x, v.y, v.z, v.w};
    unsigned short h[4], l[4];
#pragma unroll
    for (int k = 0; k < 4; ++k) {
        h[k] = f2bf(f[k]);
        l[k] = f2bf(f[k] - bf2f(h[k]));
    }
    *(uint2*)(hi + i) = *(const uint2*)h;
    *(uint2*)(lo + i) = *(const uint2*)l;
}

__global__ __launch_bounds__(256) void prep_kernel(
    unsigned long long* __restrict__ hpair, float* __restrict__ zbias,
    const float* __restrict__ W_out, unsigned short* __restrict__ Wout_bf,
    const float* __restrict__ inp,  unsigned short* __restrict__ inp_h,  unsigned short* __restrict__ inp_l,
    const float* __restrict__ Wih,  unsigned short* __restrict__ Wih_h,  unsigned short* __restrict__ Wih_l,
    const float* __restrict__ Wattn,unsigned short* __restrict__ Wattn_h,unsigned short* __restrict__ Wattn_l,
    const float* __restrict__ Wden, unsigned short* __restrict__ Wden_h, unsigned short* __restrict__ Wden_l,
    const float* __restrict__ enc,  unsigned short* __restrict__ enc_h,  unsigned short* __restrict__ enc_l)
{
    const int gid = blockIdx.x * 256 + threadIdx.x;
    const int stride = gridDim.x * 256;

    // zero hpair (2*16*512 ull) + zbias (512 f)
    for (int i = gid; i < 2 * Bdim * Hdim; i += stride) hpair[i] = 0ull;
    for (int i = gid; i < Hdim; i += stride) zbias[i] = 0.f;

    // W_out -> bf16 (16.384M elems, vec4)
    for (int i = gid * 4; i < Vdim * Hdim; i += stride * 4) {
        float4 v = *(const float4*)(W_out + i);
        unsigned short h[4] = {f2bf(v.x), f2bf(v.y), f2bf(v.z), f2bf(v.w)};
        *(uint2*)(Wout_bf + i) = *(const uint2*)h;
    }
    // splits
    for (int i = gid * 4; i < BT * Hdim;   i += stride * 4) split4(inp,   inp_h,   inp_l,   i);
    for (int i = gid * 4; i < 1536 * Hdim; i += stride * 4) split4(Wih,   Wih_h,   Wih_l,   i);
    for (int i = gid * 4; i < Hdim * 1024; i += stride * 4) split4(Wattn, Wattn_h, Wattn_l, i);
    for (int i = gid * 4; i < Hdim * 1024; i += stride * 4) split4(Wden,  Wden_h,  Wden_l,  i);
    for (int i = gid * 4; i < BT * Hdim;   i += stride * 4) split4(enc,   enc_h,   enc_l,   i);
}

// ----------------------- split-bf16 MFMA GEMM ------------------------------
// C[M x N] = act( A @ B^T + bias ); acc = Ah*Bh + Ah*Bl + Al*Bh.
// grid = (N/128, M/128), block = 256.

__global__ __launch_bounds__(256) void gemm_split(
    const unsigned short* __restrict__ Ah, const unsigned short* __restrict__ Al, int lda,
    const unsigned short* __restrict__ Bh, const unsigned short* __restrict__ Bl, int ldb,
    const float* __restrict__ bias,
    float* __restrict__ C, unsigned short* __restrict__ Cb, int ldc,
    int K, int act)
{
    __shared__ unsigned short AsH[128 * 40];
    __shared__ unsigned short AsL[128 * 40];
    __shared__ unsigned short BsH[128 * 40];
    __shared__ unsigned short BsL[128 * 40];
    const int tid = threadIdx.x;
    const int m0 = blockIdx.y * 128, n0 = blockIdx.x * 128;
    const int wave = tid >> 6, lane = tid & 63;
    const int wm = (wave >> 1) * 64, wn = (wave & 1) * 64;
    const int lrow = lane & 15, lk = (lane >> 4) * 8;

    f32x4 acc[4][4];
#pragma unroll
    for (int i = 0; i < 4; ++i)
#pragma unroll
        for (int j = 0; j < 4; ++j) acc[i][j] = (f32x4){0.f, 0.f, 0.f, 0.f};

    for (int k0 = 0; k0 < K; k0 += 32) {
#pragma unroll
        for (int i = 0; i < 2; ++i) {
            int idx = tid + i * 256;        // 0..511
            int rr = idx >> 2, kq = (idx & 3) * 8;
            size_t ao = (size_t)(m0 + rr) * lda + k0 + kq;
            size_t bo = (size_t)(n0 + rr) * ldb + k0 + kq;
            *(uint4*)(&AsH[rr * 40 + kq]) = *(const uint4*)(Ah + ao);
            *(uint4*)(&AsL[rr * 40 + kq]) = *(const uint4*)(Al + ao);
            *(uint4*)(&BsH[rr * 40 + kq]) = *(const uint4*)(Bh + bo);
            *(uint4*)(&BsL[rr * 40 + kq]) = *(const uint4*)(Bl + bo);
        }
        __syncthreads();
        bf16x8 ah[4], al[4], bh[4], bl[4];
#pragma unroll
        for (int i = 0; i < 4; ++i) {
            ah[i] = *(const bf16x8*)(&AsH[(wm + i * 16 + lrow) * 40 + lk]);
            al[i] = *(const bf16x8*)(&AsL[(wm + i * 16 + lrow) * 40 + lk]);
        }
#pragma unroll
        for (int j = 0; j < 4; ++j) {
            bh[j] = *(const bf16x8*)(&BsH[(wn + j * 16 + lrow) * 40 + lk]);
            bl[j] = *(const bf16x8*)(&BsL[(wn + j * 16 + lrow) * 40 + lk]);
        }
#pragma unroll
        for (int i = 0; i < 4; ++i)
#pragma unroll
            for (int j = 0; j < 4; ++j) {
                acc[i][j] = __builtin_amdgcn_mfma_f32_16x16x32_bf16(ah[i], bh[j], acc[i][j], 0, 0, 0);
                acc[i][j] = __builtin_amdgcn_mfma_f32_16x16x32_bf16(ah[i], bl[j], acc[i][j], 0, 0, 0);
                acc[i][j] = __builtin_amdgcn_mfma_f32_16x16x32_bf16(al[i], bh[j], acc[i][j], 0, 0, 0);
            }
        __syncthreads();
    }

    const int crow = m0 + wm + ((lane >> 4) * 4);
    const int ccol = n0 + wn + (lane & 15);
#pragma unroll
    for (int i = 0; i < 4; ++i) {
#pragma unroll
        for (int j = 0; j < 4; ++j) {
            int col = ccol + j * 16;
            float bv = bias[col];
#pragma unroll
            for (int rr = 0; rr < 4; ++rr) {
                int row = crow + i * 16 + rr;
                float v = acc[i][j][rr] + bv;
                if (act == 1) v = tanhf(v);
                if (Cb) Cb[(size_t)row * ldc + col] = f2bf(v);
                else    C [(size_t)row * ldc + col] = v;
            }
        }
    }
}

// --------------------------- persistent GRU --------------------------------
// 128 blocks x 256 threads. Block bid owns hidden units j0=bid*4..+3
// (12 W_hh rows in registers). h exchanged as (value,tag) 8B pairs via
// relaxed agent-scope atomics; consumers poll tags. No barrier, no fences.

__global__ __launch_bounds__(256) void gru_persistent(
    const float* __restrict__ xp,        // (1024,1536) rows = b*64+t
    const float* __restrict__ Whh,       // (1536,512)
    const float* __restrict__ bhh,       // (1536)
    const int*   __restrict__ lengths,   // (16)
    unsigned long long* __restrict__ hpair,  // [2][16][512] (value,tag); zeroed
    unsigned short* __restrict__ cath,   // (1024,1024) cols [0,512)
    unsigned short* __restrict__ catl,
    float* __restrict__ h_last)          // (16,512)
{
    const int bid  = blockIdx.x;
    const int tid  = threadIdx.x;
    const int wave = tid >> 6, lane = tid & 63;
    const int j0 = bid * 4;
    const int k0 = lane * 8;

    // --- W_hh slice into registers (once) ---
    float w[12][8];
#pragma unroll
    for (int g = 0; g < 3; ++g)
#pragma unroll
        for (int jj = 0; jj < 4; ++jj) {
            const float* src = Whh + (size_t)(g * 512 + j0 + jj) * Hdim + k0;
            float4 a = *(const float4*)src;
            float4 b = *(const float4*)(src + 4);
            int r = g * 4 + jj;
            w[r][0] = a.x; w[r][1] = a.y; w[r][2] = a.z; w[r][3] = a.w;
            w[r][4] = b.x; w[r][5] = b.y; w[r][6] = b.z; w[r][7] = b.w;
        }

    const int gjj = lane >> 2;        // 0..3 (valid when lane<16)
    const int gbi = lane & 3;
    const int gb  = wave * 4 + gbi;
    const int gj  = j0 + gjj;
    float bh_r = 0.f, bh_z = 0.f, bh_n = 0.f;
    int   len_b = 0;
    if (lane < 16) {
        bh_r = bhh[gj]; bh_z = bhh[512 + gj]; bh_n = bhh[1024 + gj];
        len_b = lengths[gb];
    }
    float hprev = 0.f;   // this lane's own h[gb][gj] (h0 = 0)

    for (int t = 0; t < Tdim; ++t) {
        const unsigned long long* cur = hpair + (t & 1) * (Bdim * Hdim);
        unsigned long long*       nxt = hpair + ((t + 1) & 1) * (Bdim * Hdim);

        // xp loads independent of h -> issue early
        float xr = 0.f, xz = 0.f, xn = 0.f;
        if (lane < 16) {
            const float* xrow = xp + (size_t)(gb * Tdim + t) * 1536;
            xr = xrow[gj]; xz = xrow[512 + gj]; xn = xrow[1024 + gj];
        }

        // ---- poll + load h (4 batches x 8 k each) ----
        const unsigned want = (unsigned)t;
        float hv[4][8];
        for (;;) {
            bool ok = true;
#pragma unroll
            for (int bi = 0; bi < 4; ++bi) {
                const unsigned long long* hp = cur + (wave * 4 + bi) * Hdim + k0;
#pragma unroll
                for (int q = 0; q < 8; ++q) {
                    unsigned long long u = __hip_atomic_load(
                        hp + q, __ATOMIC_RELAXED, __HIP_MEMORY_SCOPE_AGENT);
                    ok &= ((unsigned)(u >> 32) == want);
                    hv[bi][q] = __uint_as_float((unsigned)u);
                }
            }
            if (ok) break;
            __builtin_amdgcn_s_sleep(2);
        }

        // ---- matvec partials ----
        float p[12][4];
#pragma unroll
        for (int r = 0; r < 12; ++r)
#pragma unroll
            for (int bi = 0; bi < 4; ++bi) p[r][bi] = 0.f;
#pragma unroll
        for (int bi = 0; bi < 4; ++bi)
#pragma unroll
            for (int r = 0; r < 12; ++r)
#pragma unroll
                for (int k = 0; k < 8; ++k)
                    p[r][bi] += w[r][k] * hv[bi][k];

        // butterfly reduce across 64 lanes
#pragma unroll
        for (int off = 1; off < 64; off <<= 1)
#pragma unroll
            for (int r = 0; r < 12; ++r)
#pragma unroll
                for (int bi = 0; bi < 4; ++bi)
                    p[r][bi] += __shfl_xor(p[r][bi], off);

        if (lane < 16) {
            float hr = p[0 + gjj][gbi] + bh_r;
            float hz = p[4 + gjj][gbi] + bh_z;
            float hn = p[8 + gjj][gbi] + bh_n;
            float rg = 1.f / (1.f + __expf(-(xr + hr)));
            float zg = 1.f / (1.f + __expf(-(xz + hz)));
            float ng = tanhf(xn + rg * hn);
            float hnew = (1.f - zg) * ng + zg * hprev;
            bool valid = t < len_b;
            float hkeep = valid ? hnew : hprev;
            hprev = hkeep;
            unsigned long long pair =
                ((unsigned long long)(unsigned)(t + 1) << 32) |
                (unsigned long long)(unsigned)__float_as_uint(hkeep);
            __hip_atomic_store(nxt + gb * Hdim + gj, pair,
                               __ATOMIC_RELAXED, __HIP_MEMORY_SCOPE_AGENT);
            float y = valid ? hnew : 0.f;
            unsigned short yh = f2bf(y);
            size_t ci = (size_t)(gb * Tdim + t) * 1024 + gj;
            cath[ci] = yh;
            catl[ci] = f2bf(y - bf2f(yh));
            if (t == Tdim - 1) h_last[gb * Hdim + gj] = hkeep;
        }
    }
}

// ------------------------------ attention ----------------------------------

__global__ __launch_bounds__(256) void attn_kernel(
    const float* __restrict__ encp,     // (1024,512)
    const float* __restrict__ decp,     // (1024,512)
    const float* __restrict__ enc,      // (16,64,512)
    const float* __restrict__ battn,    // (512)
    const float* __restrict__ vw,       // (512)
    const float* __restrict__ vb,       // (1)
    const int* __restrict__ enc_len,    // (16)
    const int* __restrict__ dec_len,    // (16)
    unsigned short* __restrict__ cath,
    unsigned short* __restrict__ catl)
{
    const int blk = blockIdx.x;
    const int b = blk >> 6, d = blk & 63;
    const int tid = threadIdx.x;
    const size_t obase = (size_t)(b * Tdim + d) * 1024 + 512;

    if (d >= dec_len[b]) {
        for (int h = tid; h < Hdim; h += 256) { cath[obase + h] = 0; catl[obase + h] = 0; }
        return;
    }
    const int Tv = enc_len[b];

    __shared__ float part[64][4];
    __shared__ float a_lds[64];

    const int e = tid >> 2, p = tid & 3;
    float s = 0.f;
    if (e < Tv) {
        const float* ep = encp + (size_t)(b * Tdim + e) * Hdim;
        const float* dp = decp + (size_t)(b * Tdim + d) * Hdim;
        const int g0 = p * 128;
        for (int g = g0; g < g0 + 128; ++g)
            s += vw[g] * tanhf(ep[g] + dp[g] + battn[g]);
    }
    part[e][p] = s;
    __syncthreads();

    if (tid < 64) {
        const int e2 = tid;
        float en = (e2 < Tv) ? (part[e2][0] + part[e2][1] + part[e2][2] + part[e2][3] + vb[0]) : -1e30f;
        float m = en;
#pragma unroll
        for (int off = 32; off; off >>= 1) m = fmaxf(m, __shfl_xor(m, off));
        float ex = (e2 < Tv) ? __expf(en - m) : 0.f;
        float sum = ex;
#pragma unroll
        for (int off = 32; off; off >>= 1) sum += __shfl_xor(sum, off);
        a_lds[e2] = ex / sum;
    }
    __syncthreads();

    const int h = tid * 2;
    float c0 = 0.f, c1 = 0.f;
    for (int e3 = 0; e3 < Tv; ++e3) {
        float a = a_lds[e3];
        float2 ev = *(const float2*)(enc + (size_t)(b * Tdim + e3) * Hdim + h);
        c0 += a * ev.x; c1 += a * ev.y;
    }
    unsigned short h0 = f2bf(c0), h1 = f2bf(c1);
    cath[obase + h]     = h0;  catl[obase + h]     = f2bf(c0 - bf2f(h0));
    cath[obase + h + 1] = h1;  catl[obase + h + 1] = f2bf(c1 - bf2f(h1));
}

// --------------------------- logits bf16 MFMA GEMM -------------------------

__global__ __launch_bounds__(256) void gemm_logits(
    const unsigned short* __restrict__ A,
    const unsigned short* __restrict__ B,
    const float* __restrict__ bias,
    float* __restrict__ C)
{
    const int K = Hdim;
    __shared__ unsigned short As[128 * 40];
    __shared__ unsigned short Bs[128 * 40];
    const int tid = threadIdx.x;
    const int m0 = blockIdx.y * 128, n0 = blockIdx.x * 128;
    const int wave = tid >> 6, lane = tid & 63;
    const int wm = (wave >> 1) * 64, wn = (wave & 1) * 64;
    const int lrow = lane & 15, lk = (lane >> 4) * 8;

    f32x4 acc[4][4];
#pragma unroll
    for (int i = 0; i < 4; ++i)
#pragma unroll
        for (int j = 0; j < 4; ++j) acc[i][j] = (f32x4){0.f, 0.f, 0.f, 0.f};

    for (int k0 = 0; k0 < K; k0 += 32) {
#pragma unroll
        for (int i = 0; i < 2; ++i) {
            int idx = tid + i * 256;        // 0..511
            int rr = idx >> 2, kq = (idx & 3) * 8;
            *(uint4*)(&As[rr * 40 + kq]) = *(const uint4*)(A + (size_t)(m0 + rr) * K + k0 + kq);
            *(uint4*)(&Bs[rr * 40 + kq]) = *(const uint4*)(B + (size_t)(n0 + rr) * K + k0 + kq);
        }
        __syncthreads();
        bf16x8 af[4], bf[4];
#pragma unroll
        for (int i = 0; i < 4; ++i) af[i] = *(const bf16x8*)(&As[(wm + i * 16 + lrow) * 40 + lk]);
#pragma unroll
        for (int j = 0; j < 4; ++j) bf[j] = *(const bf16x8*)(&Bs[(wn + j * 16 + lrow) * 40 + lk]);
#pragma unroll
        for (int i = 0; i < 4; ++i)
#pragma unroll
            for (int j = 0; j < 4; ++j)
                acc[i][j] = __builtin_amdgcn_mfma_f32_16x16x32_bf16(af[i], bf[j], acc[i][j], 0, 0, 0);
        __syncthreads();
    }

    const int crow = m0 + wm + ((lane >> 4) * 4);
    const int ccol = n0 + wn + (lane & 15);
#pragma unroll
    for (int i = 0; i < 4; ++i) {
#pragma unroll
        for (int j = 0; j < 4; ++j) {
            int col = ccol + j * 16;
            float bv = bias[col];
#pragma unroll
            for (int rr = 0; rr < 4; ++rr) {
                int row = crow + i * 16 + rr;
                C[(size_t)row * Vdim + col] = acc[i][j][rr] + bv;
            }
        }
    }
}

// ------------------------------- launcher ----------------------------------

extern "C" void kernel_launch(void* const* d_in, const int* in_sizes, int n_in,
                              void* d_out, int out_size, void* d_ws, size_t ws_size,
                              hipStream_t stream) {
    (void)in_sizes; (void)n_in; (void)out_size; (void)ws_size;

    const float* input_seqs  = (const float*)d_in[0];
    const int*   input_len   = (const int*)  d_in[1];
    const float* enc_out     = (const float*)d_in[2];
    const int*   enc_len     = (const int*)  d_in[3];
    const float* W_ih        = (const float*)d_in[4];
    const float* W_hh        = (const float*)d_in[5];
    const float* b_ih        = (const float*)d_in[6];
    const float* b_hh        = (const float*)d_in[7];
    const float* W_attn      = (const float*)d_in[8];
    const float* b_attn      = (const float*)d_in[9];
    const float* v_w         = (const float*)d_in[10];
    const float* v_b         = (const float*)d_in[11];
    const float* W_dense     = (const float*)d_in[12];
    const float* b_dense     = (const float*)d_in[13];
    const float* W_out       = (const float*)d_in[14];
    const float* b_out       = (const float*)d_in[15];

    float* logits = (float*)d_out;                        // (1024, 32000)
    float* h_last = (float*)d_out + (size_t)BT * Vdim;    // (16, 512)

    // ---- workspace layout ----
    float* ws    = (float*)d_ws;
    float* xp    = ws;                         // 1572864 f
    float* encp  = xp   + 1572864;             // 524288 f
    float* decp  = encp + 524288;              // 524288 f
    unsigned long long* hpair = (unsigned long long*)(decp + 524288);  // 16384 ull
    float* zbias = (float*)(hpair + 16384);    // 512 f
    unsigned short* U0 = (unsigned short*)(zbias + 512);
    unsigned short* inp_h   = U0;               // 524288
    unsigned short* inp_l   = U0 + 524288;      // 524288
    unsigned short* Wih_h   = U0 + 1048576;     // 786432
    unsigned short* Wih_l   = U0 + 1835008;     // 786432
    unsigned short* Wattn_h = U0 + 2621440;     // 524288
    unsigned short* Wattn_l = U0 + 3145728;     // 524288
    unsigned short* Wden_h  = U0 + 3670016;     // 524288
    unsigned short* Wden_l  = U0 + 4194304;     // 524288
    unsigned short* enc_h   = U0 + 4718592;     // 524288
    unsigned short* enc_l   = U0 + 5242880;     // 524288
    unsigned short* Wout_bf = U0 + 5767168;     // 16384000
    // cat hi/lo alias the inp/Wih splits (dead after x_proj):
    unsigned short* cath = U0;                  // 1048576 (1024x1024)
    unsigned short* catl = U0 + 1048576;        // 1048576
    // dense_bf aliases encp (dead after attn):
    unsigned short* dense_bf = (unsigned short*)encp;   // 524288

    // 1. fused prep: zero hpair+zbias, W_out->bf16, 5 hi/lo splits
    prep_kernel<<<2048, 256, 0, stream>>>(
        hpair, zbias, W_out, Wout_bf,
        input_seqs, inp_h, inp_l,
        W_ih, Wih_h, Wih_l,
        W_attn, Wattn_h, Wattn_l,
        W_dense, Wden_h, Wden_l,
        enc_out, enc_h, enc_l);

    // 2. x_proj = input_seqs @ W_ih^T + b_ih   (1024 x 1536, K=512)
    gemm_split<<<dim3(1536 / 128, BT / 128), 256, 0, stream>>>(
        inp_h, inp_l, Hdim, Wih_h, Wih_l, Hdim, b_ih, xp, nullptr, 1536, Hdim, 0);

    // 3. enc_p = enc @ We^T  (We = W_attn[:, :512], ldb=1024), no bias
    gemm_split<<<dim3(Hdim / 128, BT / 128), 256, 0, stream>>>(
        enc_h, enc_l, Hdim, Wattn_h, Wattn_l, 1024, zbias, encp, nullptr, Hdim, Hdim, 0);

    // 4. GRU (persistent, self-timed dataflow; writes cat cols [0,512), h_last)
    gru_persistent<<<GRU_BLOCKS, 256, 0, stream>>>(
        xp, W_hh, b_hh, input_len, hpair, cath, catl, h_last);

    // 5. dec_p = dec_out @ Wd^T (A = cat[:, :512] hi/lo, lda=1024), no bias
    gemm_split<<<dim3(Hdim / 128, BT / 128), 256, 0, stream>>>(
        cath, catl, 1024, Wattn_h + 512, Wattn_l + 512, 1024, zbias, decp, nullptr, Hdim, Hdim, 0);

    // 6. attention -> cat cols [512,1024) hi/lo bf16
    attn_kernel<<<BT, 256, 0, stream>>>(encp, decp, enc_out, b_attn, v_w, v_b,
                                        enc_len, input_len, cath, catl);

    // 7. dense = tanh(cat @ W_dense^T + b_dense) -> bf16 directly (K=1024)
    gemm_split<<<dim3(Hdim / 128, BT / 128), 256, 0, stream>>>(
        cath, catl, 1024, Wden_h, Wden_l, 1024, b_dense, nullptr, dense_bf, Hdim, 1024, 1);

    // 8. logits = dense @ W_out^T + b_out  (1024 x 32000, K=512)
    gemm_logits<<<dim3(Vdim / 128, BT / 128), 256, 0, stream>>>(
        dense_bf, Wout_bf, b_out, logits);
}